// Round 4
// baseline (515.599 us; speedup 1.0000x reference)
//
#include <hip/hip_runtime.h>
#include <hip/hip_cooperative_groups.h>
#include <hip/hip_bf16.h>
#include <stdint.h>

namespace cg = cooperative_groups;

typedef __attribute__((ext_vector_type(8))) short bf16x8;
typedef __attribute__((ext_vector_type(4))) float f32x4;
typedef __attribute__((ext_vector_type(4))) unsigned int u32x4;
typedef __attribute__((ext_vector_type(2))) unsigned int u32x2;
typedef unsigned short u16;
typedef unsigned int u32;
typedef unsigned long long u64;

#define N_NODES 8192
#define N_EDGES 1024
#define F_DIM   256
// elist: edge degree ~ Binom(8192,.05) mean 409.6 sd 19.7, max over 1024
// draws ~473 -> 512 safe. nlist: node degree mean 51.2 sd 7.0, max ~77 -> 128.
#define EMAX 512
#define NMAX 128
#define NSEG 256        // 256 segments x 32 rows (1 segment per block)
#define SEGR 32
#define NBLK 256
#define NTHR 512

__device__ __forceinline__ u16 f2bf(float f) {
    union { float f; u32 u; } v; v.f = f;
    u32 u = v.u;
    u = (u + 0x7FFFu + ((u >> 16) & 1u)) >> 16;   // round-nearest-even
    return (u16)u;
}
__device__ __forceinline__ float bflo(u32 p) {
    union { u32 u; float f; } v; v.u = p << 16; return v.f;
}
__device__ __forceinline__ float bfhi(u32 p) {
    union { u32 u; float f; } v; v.u = p & 0xffff0000u; return v.f;
}

// LDS overlay. hmask persists phase1 -> phase3 (saves the 33.5MB H re-read).
struct SMem {
    u16 hmask[SEGR][64];              // 4 KB: nz bitmask of this block's 32 rows
    union {
        u32 colp[8][64][4];           // 8 KB  phase1 col-count reduce
        u32 sums[64][8];              // 2 KB  phase2 chunk sums
        struct {                      // phase4 (spmm1)
            u32   lst[4][256];        // 4 edges x 512 u16 indices
            float red[4][4][256];     // 16 KB cross-wave reduce
        } p4;
        struct {                      // phase5 (gemm_we)
            u16 As[64 * 72];
            u16 Bs[64 * 72];          // 18.4 KB
        } p5;
        struct {                      // phase6 (spmm2)
            u32   nl[2048];           // 32 nodes x 128 u16 indices (8 KB)
            float red2[8][2][256];    // 16 KB
        } p6;
    } u;
};

// ---------------------------------------------------------------------------
// mega — the whole HGNN layer in ONE cooperative dispatch, 6 phases:
//  1) H pass: bitmasks->LDS, nlist (ballot-scan), dv, Xs=bf16(X*rsqrt(dv)),
//     per-segment column counts (plain coalesced stores; no atomics/memset)
//  2) per-edge prefix over 256 segments (16 blocks, 2-level scan) -> base,cnt_e
//  3) scatter: compact sorted elist from LDS bitmasks + base (no H re-read)
//  4) spmm1: M[e][:] = sum_{n in e} Xs[n][:]   (gather, L2-resident Xs)
//  5) gemm_we: M2[e][j] = bf16( (M[e]/de[e]) . W[j] )   (MFMA, 64 blocks)
//  6) spmm2: out[n][:] = rsqrt(dv[n]) * sum_{e in n} M2[e][:] + b
// ---------------------------------------------------------------------------
__global__ void __launch_bounds__(NTHR) mega(
    const float* __restrict__ H, const float* __restrict__ X,
    const float* __restrict__ W, const float* __restrict__ bias,
    float* __restrict__ out,
    float* __restrict__ dv, u32* __restrict__ cnt_e,
    u16* __restrict__ cnt_seg, u16* __restrict__ base,
    u16* __restrict__ nlist, u16* __restrict__ elist,
    u16* __restrict__ Xs, float* __restrict__ M, u16* __restrict__ M2)
{
    __shared__ SMem sm;
    cg::grid_group grid = cg::this_grid();
    const int tid = threadIdx.x;
    const int blk = blockIdx.x;
    const int wv = tid >> 6;
    const int lane = tid & 63;

    // ---------------- phase 1: H pass ----------------
    {
        const int n0 = blk * SEGR + wv * 4;
        f32x4 hv[4][4], xv[4];
#pragma unroll
        for (int r = 0; r < 4; ++r) {
            const int n = n0 + r;
#pragma unroll
            for (int q = 0; q < 4; ++q)
                hv[r][q] = *(const f32x4*)(&H[(size_t)n * N_EDGES + q * 256 + lane * 4]);
            xv[r] = *(const f32x4*)(&X[(size_t)n * F_DIM + lane * 4]);
        }
        u32 cpk[4] = {0u, 0u, 0u, 0u};
#pragma unroll
        for (int r = 0; r < 4; ++r) {
            const int n = n0 + r;
            u32 m16 = 0u;
#pragma unroll
            for (int q = 0; q < 4; ++q)
#pragma unroll
                for (int j = 0; j < 4; ++j) {
                    const u32 nz = (hv[r][q][j] != 0.f) ? 1u : 0u;
                    m16 |= nz << (q * 4 + j);
                    cpk[q] += nz << (8 * j);
                }
            sm.hmask[wv * 4 + r][lane] = (u16)m16;
            const u32 cl = (u32)__popc(m16);
            u32 x = cl;
#pragma unroll
            for (int d = 1; d < 64; d <<= 1) {
                const u32 t = __shfl_up(x, d, 64);
                if (lane >= d) x += t;
            }
            const u32 total = __shfl(x, 63, 64);
            u32 pos = x - cl;                   // exclusive prefix
            u16* nrow = &nlist[(size_t)n * NMAX];
            u32 m = m16;
            while (m) {
                const int bidx = __builtin_ctz(m);
                m &= m - 1;
                const int col = ((bidx >> 2) << 8) + lane * 4 + (bidx & 3);
                if (pos < NMAX) nrow[pos] = (u16)col;
                ++pos;
            }
            if (lane == 0) dv[n] = (float)total;
            const float s = rsqrtf((float)total);
            u32x2 pk;
            pk[0] = (u32)f2bf(xv[r][0] * s) | ((u32)f2bf(xv[r][1] * s) << 16);
            pk[1] = (u32)f2bf(xv[r][2] * s) | ((u32)f2bf(xv[r][3] * s) << 16);
            *(u32x2*)(&Xs[(size_t)n * F_DIM + lane * 4]) = pk;
        }
#pragma unroll
        for (int q = 0; q < 4; ++q) sm.u.colp[wv][lane][q] = cpk[q];
        __syncthreads();
        if (tid < 256) {
            const int q = tid >> 6, l = tid & 63;
            u32 sum = 0;
#pragma unroll
            for (int w = 0; w < 8; ++w) sum += sm.u.colp[w][l][q];
            // 4 consecutive cols, counts <=32 each: pack to 4 u16, one 8B store
            u32x2 st;
            st[0] = (sum & 0xffu) | (((sum >> 8) & 0xffu) << 16);
            st[1] = ((sum >> 16) & 0xffu) | (((sum >> 24) & 0xffu) << 16);
            *(u32x2*)(&cnt_seg[(size_t)blk * N_EDGES + q * 256 + l * 4]) = st;
        }
    }
    __threadfence();
    grid.sync();

    // ---------------- phase 2: prefix (16 blocks) ----------------
    if (blk < 16) {
        const int el = tid & 63;            // edge within this block's 64
        const int ch = tid >> 6;            // chunk of 32 segments
        const int e = blk * 64 + el;
        u32 s1 = 0;
#pragma unroll 8
        for (int k = 0; k < 32; ++k)
            s1 += cnt_seg[(size_t)(ch * 32 + k) * N_EDGES + e];
        sm.u.sums[el][ch] = s1;
        __syncthreads();
        u32 run = 0;
        for (int cc = 0; cc < ch; ++cc) run += sm.u.sums[el][cc];
#pragma unroll 8
        for (int k = 0; k < 32; ++k) {
            const size_t idx = (size_t)(ch * 32 + k) * N_EDGES + e;
            const u32 cv = cnt_seg[idx];
            base[idx] = (u16)run;
            run += cv;
        }
        if (ch == 7) cnt_e[e] = run;
    }
    __threadfence();
    grid.sync();

    // ---------------- phase 3: scatter from LDS bitmasks ----------------
    {
        const int c0 = tid * 2;
        const u32 bb = *(const u32*)(&base[(size_t)blk * N_EDGES + c0]);
        u32 b0 = bb & 0xffffu, b1 = bb >> 16;
        const int q = c0 >> 8;
        const int widx = (c0 & 255) >> 2;
        const int bit0 = q * 4 + (c0 & 3);
        const int r0g = blk * SEGR;
        u16* el0 = &elist[(size_t)c0 * EMAX];
        u16* el1 = &elist[(size_t)(c0 + 1) * EMAX];
#pragma unroll 8
        for (int r = 0; r < SEGR; ++r) {
            const u32 mrow = sm.hmask[r][widx];
            if ((mrow >> bit0) & 1u) { if (b0 < EMAX) el0[b0] = (u16)(r0g + r); b0++; }
            if ((mrow >> (bit0 + 1)) & 1u) { if (b1 < EMAX) el1[b1] = (u16)(r0g + r); b1++; }
        }
    }
    __threadfence();
    grid.sync();

    // ---------------- phase 4: spmm1 ----------------
    {
        const int g = wv >> 1;              // 4 edge-groups x 2 waves
        const int w2 = wv & 1;
        const int e = blk * 4 + g;
        const int tg = w2 * 64 + lane;      // 0..127 within group
        sm.u.p4.lst[g][tg]       = ((const u32*)&elist[(size_t)e * EMAX])[tg];
        sm.u.p4.lst[g][tg + 128] = ((const u32*)&elist[(size_t)e * EMAX])[tg + 128];
        const int cnt = min((int)cnt_e[e], EMAX);
        __syncthreads();
        const int half = lane >> 5, l32 = lane & 31;
        const int npairs = (cnt + 1) >> 1;
        const int len = (npairs + 1) >> 1;
        const int p0 = w2 * len, p1 = min(p0 + len, npairs);
        const u16* lst16 = (const u16*)sm.u.p4.lst[g];
        float a[8] = {};
#pragma unroll 8
        for (int p = p0; p < p1; ++p) {
            const int idx = 2 * p + half;
            if (idx < cnt) {
                const int nn = lst16[idx];
                const u32x4 pk = *(const u32x4*)(&Xs[(size_t)nn * F_DIM + l32 * 8]);
#pragma unroll
                for (int k = 0; k < 4; ++k) { a[2*k] += bflo(pk[k]); a[2*k+1] += bfhi(pk[k]); }
            }
        }
        f32x4 r0 = {a[0], a[1], a[2], a[3]};
        f32x4 r1 = {a[4], a[5], a[6], a[7]};
        *(f32x4*)(&sm.u.p4.red[g][w2 * 2 + half][l32 * 8]) = r0;
        *(f32x4*)(&sm.u.p4.red[g][w2 * 2 + half][l32 * 8 + 4]) = r1;
        __syncthreads();
        const int g2 = tid >> 7, f = tid & 127;
        float s0 = 0.f, s1 = 0.f;
#pragma unroll
        for (int w = 0; w < 4; ++w) {
            s0 += sm.u.p4.red[g2][w][f];
            s1 += sm.u.p4.red[g2][w][f + 128];
        }
        M[(size_t)(blk * 4 + g2) * F_DIM + f] = s0;
        M[(size_t)(blk * 4 + g2) * F_DIM + f + 128] = s1;
    }
    __threadfence();
    grid.sync();

    // ---------------- phase 5: gemm_we (64 blocks, 8 waves) ----------------
    if (blk < 64) {
        const int e0 = (blk >> 2) * 64;
        const int j0 = (blk & 3) * 64;
        const int row16 = lane & 15, quad = lane >> 4;
        const int wm = wv >> 2, wn = wv & 3;      // 2 x 4 wave grid
        const int sr = tid >> 3;                  // 0..63 tile row
        const int fb = (tid & 7) * 8;             // 8-float chunk
        const float dei = 1.f / (float)cnt_e[e0 + sr];
        f32x4 acc[2] = {};
        for (int k = 0; k < 256; k += 64) {
            __syncthreads();
            f32x4 m0 = *(const f32x4*)(&M[(size_t)(e0 + sr) * F_DIM + k + fb]);
            f32x4 m1 = *(const f32x4*)(&M[(size_t)(e0 + sr) * F_DIM + k + fb + 4]);
            u32x2 pk;
            pk[0] = (u32)f2bf(m0[0] * dei) | ((u32)f2bf(m0[1] * dei) << 16);
            pk[1] = (u32)f2bf(m0[2] * dei) | ((u32)f2bf(m0[3] * dei) << 16);
            *(u32x2*)(&sm.u.p5.As[sr * 72 + fb]) = pk;
            pk[0] = (u32)f2bf(m1[0] * dei) | ((u32)f2bf(m1[1] * dei) << 16);
            pk[1] = (u32)f2bf(m1[2] * dei) | ((u32)f2bf(m1[3] * dei) << 16);
            *(u32x2*)(&sm.u.p5.As[sr * 72 + fb + 4]) = pk;
            f32x4 w0 = *(const f32x4*)(&W[(size_t)(j0 + sr) * F_DIM + k + fb]);
            f32x4 w1 = *(const f32x4*)(&W[(size_t)(j0 + sr) * F_DIM + k + fb + 4]);
            pk[0] = (u32)f2bf(w0[0]) | ((u32)f2bf(w0[1]) << 16);
            pk[1] = (u32)f2bf(w0[2]) | ((u32)f2bf(w0[3]) << 16);
            *(u32x2*)(&sm.u.p5.Bs[sr * 72 + fb]) = pk;
            pk[0] = (u32)f2bf(w1[0]) | ((u32)f2bf(w1[1]) << 16);
            pk[1] = (u32)f2bf(w1[2]) | ((u32)f2bf(w1[3]) << 16);
            *(u32x2*)(&sm.u.p5.Bs[sr * 72 + fb + 4]) = pk;
            __syncthreads();
#pragma unroll
            for (int ks = 0; ks < 2; ++ks) {
                bf16x8 af[2], bf;
#pragma unroll
                for (int t = 0; t < 2; ++t)
                    af[t] = *(const bf16x8*)(&sm.u.p5.As[(wm * 32 + t * 16 + row16) * 72 + ks * 32 + quad * 8]);
                bf = *(const bf16x8*)(&sm.u.p5.Bs[(wn * 16 + row16) * 72 + ks * 32 + quad * 8]);
#pragma unroll
                for (int t = 0; t < 2; ++t)
                    acc[t] = __builtin_amdgcn_mfma_f32_16x16x32_bf16(af[t], bf, acc[t], 0, 0, 0);
            }
        }
#pragma unroll
        for (int t = 0; t < 2; ++t)
#pragma unroll
            for (int r = 0; r < 4; ++r)
                M2[(size_t)(e0 + wm * 32 + t * 16 + quad * 4 + r) * F_DIM + j0 + wn * 16 + row16] =
                    f2bf(acc[t][r]);
    }
    __threadfence();
    grid.sync();

    // ---------------- phase 6: spmm2 ----------------
    {
        const u32* gn = (const u32*)&nlist[(size_t)blk * 32 * NMAX];
#pragma unroll
        for (int k = 0; k < 4; ++k) sm.u.p6.nl[tid + k * 512] = gn[tid + k * 512];
        __syncthreads();
        const int half = lane >> 5, l32 = lane & 31;
        const f32x4 bb4 = *(const f32x4*)(&bias[lane * 4]);
#pragma unroll
        for (int rnd = 0; rnd < 4; ++rnd) {
            const int nloc = rnd * 8 + wv;
            const int n = blk * 32 + nloc;
            const float dvn = dv[n];
            const int cnt = min((int)dvn, NMAX);
            const u16* lst = (const u16*)&sm.u.p6.nl[nloc * 64];
            float a[8] = {};
            const int npairs = (cnt + 1) >> 1;
#pragma unroll 8
            for (int p = 0; p < npairs; ++p) {
                const int idx = 2 * p + half;
                if (idx < cnt) {
                    const int e = lst[idx];
                    const u32x4 pk = *(const u32x4*)(&M2[(size_t)e * F_DIM + l32 * 8]);
#pragma unroll
                    for (int k = 0; k < 4; ++k) { a[2*k] += bflo(pk[k]); a[2*k+1] += bfhi(pk[k]); }
                }
            }
            f32x4 r0 = {a[0], a[1], a[2], a[3]};
            f32x4 r1 = {a[4], a[5], a[6], a[7]};
            *(f32x4*)(&sm.u.p6.red2[wv][half][l32 * 8]) = r0;
            *(f32x4*)(&sm.u.p6.red2[wv][half][l32 * 8 + 4]) = r1;
            // same-wave producer/consumer: lgkmcnt ordering suffices
            const float s = rsqrtf(dvn);
            f32x4 r;
#pragma unroll
            for (int k = 0; k < 4; ++k)
                r[k] = (sm.u.p6.red2[wv][0][lane * 4 + k] +
                        sm.u.p6.red2[wv][1][lane * 4 + k]) * s + bb4[k];
            *(f32x4*)(&out[(size_t)n * F_DIM + lane * 4]) = r;
        }
    }
}

// ---------------------------------------------------------------------------
extern "C" void kernel_launch(void* const* d_in, const int* in_sizes, int n_in,
                              void* d_out, int out_size, void* d_ws, size_t ws_size,
                              hipStream_t stream) {
    (void)in_sizes; (void)n_in; (void)out_size; (void)ws_size;
    const float* X = (const float*)d_in[0];   // [8192 x 256]
    const float* H = (const float*)d_in[1];   // [8192 x 1024]
    const float* W = (const float*)d_in[2];   // [256 x 256]
    const float* b = (const float*)d_in[3];   // [256]
    float* out = (float*)d_out;               // [8192 x 256] fp32

    char* ws = (char*)d_ws;
    float* dv      = (float*)(ws);             // 32 KB  [8192]
    u32*   cnt_e   = (u32*)(ws + 0x8000);      // 4 KB   [1024]
    u16*   cnt_seg = (u16*)(ws + 0x10000);     // 512 KB [256][1024] seg-major
    u16*   base    = (u16*)(ws + 0x90000);     // 512 KB [256][1024] seg-major
    u16*   nlist   = (u16*)(ws + 0x110000);    // 2 MB   [8192][128]
    u16*   elist   = (u16*)(ws + 0x310000);    // 1 MB   [1024][512]
    u16*   Xs      = (u16*)(ws + 0x410000);    // 4 MB   [8192][256]
    float* M       = (float*)(ws + 0x810000);  // 1 MB   [1024][256]
    u16*   M2      = (u16*)(ws + 0x910000);    // 512 KB [1024][256]

    void* args[14] = {
        (void*)&H, (void*)&X, (void*)&W, (void*)&b, (void*)&out,
        (void*)&dv, (void*)&cnt_e, (void*)&cnt_seg, (void*)&base,
        (void*)&nlist, (void*)&elist, (void*)&Xs, (void*)&M, (void*)&M2
    };
    hipLaunchCooperativeKernel((void*)mega, dim3(NBLK), dim3(NTHR), args, 0, stream);
}

// Round 5
// 132.315 us; speedup vs baseline: 3.8968x; 3.8968x over previous
//
#include <hip/hip_runtime.h>
#include <hip/hip_bf16.h>
#include <stdint.h>

typedef __attribute__((ext_vector_type(8))) short bf16x8;
typedef __attribute__((ext_vector_type(4))) float f32x4;
typedef __attribute__((ext_vector_type(4))) unsigned int u32x4;
typedef __attribute__((ext_vector_type(2))) unsigned int u32x2;
typedef unsigned short u16;
typedef unsigned int u32;
typedef unsigned long long u64;

#define N_NODES 8192
#define N_EDGES 1024
#define F_DIM   256
#define NMAX 128        // node degree ~ Binom(1024,.05): mean 51.2 sd 7.0, max over 8192 draws ~77
#define NSEG 256        // 256 segments x 32 rows; HbT[e][seg] bit r = H[seg*32+r][e]

__device__ __forceinline__ u16 f2bf(float f) {
    union { float f; u32 u; } v; v.f = f;
    u32 u = v.u;
    u = (u + 0x7FFFu + ((u >> 16) & 1u)) >> 16;   // round-nearest-even
    return (u16)u;
}
__device__ __forceinline__ float bflo(u32 p) {
    union { u32 u; float f; } v; v.u = p << 16; return v.f;
}
__device__ __forceinline__ float bfhi(u32 p) {
    union { u32 u; float f; } v; v.u = p & 0xffff0000u; return v.f;
}

// ---------------------------------------------------------------------------
// prep — ONE pass over H (33.5 MB, only cold HBM read). Block = 32 rows,
// 8 waves x 4 rows, all loads register-staged up-front. Produces:
//   dv[n]        row popcounts (plain store)
//   nlist[n][.]  compact node->edge lists via ballot-free wave scan
//   Xs[n][f]     bf16(X[n][f]*rsqrt(dv[n]))
//   HbT[e][seg]  edge-major bitmask: ONE u32 word per edge per block, plain
//                store — this replaces cnt_seg/prefix/scatter/elist entirely.
// Zero atomics, zero memsets in the whole pipeline.
// ---------------------------------------------------------------------------
__global__ __launch_bounds__(512) void prep(
    const float* __restrict__ H, const float* __restrict__ X,
    float* __restrict__ dv, u16* __restrict__ nlist,
    u16* __restrict__ Xs, u32* __restrict__ HbT) {
    __shared__ u16 hmask[32][64];
    const int tid = threadIdx.x;
    const int wv = tid >> 6;
    const int lane = tid & 63;
    const int blk = blockIdx.x;
    const int n0 = blk * 32 + wv * 4;

    f32x4 hv[4][4], xv[4];
#pragma unroll
    for (int r = 0; r < 4; ++r) {
        const int n = n0 + r;
#pragma unroll
        for (int q = 0; q < 4; ++q)
            hv[r][q] = *(const f32x4*)(&H[(size_t)n * N_EDGES + q * 256 + lane * 4]);
        xv[r] = *(const f32x4*)(&X[(size_t)n * F_DIM + lane * 4]);
    }

#pragma unroll
    for (int r = 0; r < 4; ++r) {
        const int n = n0 + r;
        u32 m16 = 0u;
#pragma unroll
        for (int q = 0; q < 4; ++q)
#pragma unroll
            for (int j = 0; j < 4; ++j)
                m16 |= ((hv[r][q][j] != 0.f) ? 1u : 0u) << (q * 4 + j);
        hmask[wv * 4 + r][lane] = (u16)m16;
        const u32 cl = (u32)__popc(m16);
        u32 x = cl;
#pragma unroll
        for (int d = 1; d < 64; d <<= 1) {
            const u32 t = __shfl_up(x, d, 64);
            if (lane >= d) x += t;
        }
        const u32 total = __shfl(x, 63, 64);
        u32 pos = x - cl;                 // exclusive prefix
        u16* nrow = &nlist[(size_t)n * NMAX];
        u32 m = m16;
        while (m) {
            const int bidx = __builtin_ctz(m);
            m &= m - 1;
            const int col = ((bidx >> 2) << 8) + lane * 4 + (bidx & 3);
            if (pos < NMAX) nrow[pos] = (u16)col;
            ++pos;
        }
        if (lane == 0) dv[n] = (float)total;
        const float s = rsqrtf((float)total);
        u32x2 pk;
        pk[0] = (u32)f2bf(xv[r][0] * s) | ((u32)f2bf(xv[r][1] * s) << 16);
        pk[1] = (u32)f2bf(xv[r][2] * s) | ((u32)f2bf(xv[r][3] * s) << 16);
        *(u32x2*)(&Xs[(size_t)n * F_DIM + lane * 4]) = pk;
    }
    __syncthreads();
    // edge-major bitmask words: thread t -> edges t and t+512
#pragma unroll
    for (int eo = 0; eo < 2; ++eo) {
        const int e = tid + eo * 512;
        const int widx = (e & 255) >> 2;          // lane that owns this col
        const int bit = ((e >> 8) << 2) + (e & 3); // bit within that lane's m16
        u32 w = 0u;
#pragma unroll
        for (int r = 0; r < 32; ++r)
            w |= (u32)((hmask[r][widx] >> bit) & 1u) << r;
        HbT[(size_t)e * NSEG + blk] = w;
    }
}

// ---------------------------------------------------------------------------
// spmm1 — Mb[e][f] = bf16( (1/de) * sum_{n in e} Xs[n][f] ). Block per edge,
// 8 waves (32 waves/CU). Stages the edge's 256 bitmask words (1 KB) in LDS;
// each wave expands set-bits of its 32 words with a uniform ctz loop, halves
// of the wave take alternating bits -> 2 gathered rows (2x512 B) in flight
// per step. de = sum of popcounts (exact), computed in-block. Plane-split
// reduction layout: 16 B lane stride -> conflict-free minimum.
// ---------------------------------------------------------------------------
__global__ __launch_bounds__(512) void spmm1(
    const u16* __restrict__ Xs, const u32* __restrict__ HbT,
    u16* __restrict__ Mb) {
    __shared__ u32 words[NSEG];
    __shared__ float red[16][2][128];
    __shared__ u32 wcnt[8];
    const int tid = threadIdx.x;
    const int wv = tid >> 6;
    const int lane = tid & 63;
    const int e = blockIdx.x;
    if (tid < NSEG) words[tid] = HbT[(size_t)e * NSEG + tid];
    __syncthreads();
    const int half = lane >> 5, l32 = lane & 31;
    float a[8] = {};
    u32 cnt = 0;
    for (int s = wv * 32; s < wv * 32 + 32; ++s) {
        u32 w = words[s];
        cnt += (u32)__popc(w);
        const int nb = s * 32;
        while (w) {
            const int b0 = __builtin_ctz(w); w &= w - 1;
            const int b1 = w ? __builtin_ctz(w) : -1;
            if (w) w &= w - 1;
            const int b = half ? b1 : b0;
            if (b >= 0) {
                const int n = nb + b;
                const u32x4 pk = *(const u32x4*)(&Xs[(size_t)n * F_DIM + l32 * 8]);
                a[0] += bflo(pk[0]); a[1] += bfhi(pk[0]);
                a[2] += bflo(pk[1]); a[3] += bfhi(pk[1]);
                a[4] += bflo(pk[2]); a[5] += bfhi(pk[2]);
                a[6] += bflo(pk[3]); a[7] += bfhi(pk[3]);
            }
        }
    }
    const int ws = wv * 2 + half;
    f32x4 r0 = {a[0], a[1], a[2], a[3]};
    f32x4 r1 = {a[4], a[5], a[6], a[7]};
    *(f32x4*)(&red[ws][0][l32 * 4]) = r0;   // cols (i>>2)*8 + (i&3)
    *(f32x4*)(&red[ws][1][l32 * 4]) = r1;   // cols (i>>2)*8 + 4 + (i&3)
    if (lane == 0) wcnt[wv] = cnt;
    __syncthreads();
    if (tid < F_DIM) {
        const int f = tid;
        const int pl = (f >> 2) & 1;
        const int ix = ((f >> 3) << 2) | (f & 3);
        float s = 0.f;
#pragma unroll
        for (int w = 0; w < 16; ++w) s += red[w][pl][ix];
        u32 de = 0;
#pragma unroll
        for (int w = 0; w < 8; ++w) de += wcnt[w];
        Mb[(size_t)e * F_DIM + f] = f2bf(s / (float)de);
    }
}

// ---------------------------------------------------------------------------
// gemm_we — M2[e][j] = bf16( sum_f Mb[e][f] * W[j][f] ). A is already bf16
// (de folded in by spmm1): pure copy staging. Tiny dense MFMA.
// ---------------------------------------------------------------------------
__global__ __launch_bounds__(256) void gemm_we(
    const u16* __restrict__ Mb, const float* __restrict__ W,
    u16* __restrict__ M2) {
    __shared__ u16 As[64 * 72];
    __shared__ u16 Bs[64 * 72];
    const int tid = threadIdx.x;
    const int lane = tid & 63;
    const int wave = tid >> 6;
    const int wm = wave >> 1, wn = wave & 1;
    const int row16 = lane & 15;
    const int quad = lane >> 4;

    const int e0 = blockIdx.y * 64;
    const int j0 = blockIdx.x * 64;

    const int sr = tid >> 2;
    const int fb = (tid & 3) * 16;

    f32x4 acc[2][2] = {};

    for (int k = 0; k < 256; k += 64) {
        const u32x4 a0 = *(const u32x4*)(&Mb[(size_t)(e0 + sr) * F_DIM + k + fb]);
        const u32x4 a1 = *(const u32x4*)(&Mb[(size_t)(e0 + sr) * F_DIM + k + fb + 8]);
        *(u32x4*)(&As[sr * 72 + fb]) = a0;
        *(u32x4*)(&As[sr * 72 + fb + 8]) = a1;
#pragma unroll
        for (int s2 = 0; s2 < 4; ++s2) {
            f32x4 w = *(const f32x4*)(&W[(size_t)(j0 + sr) * F_DIM + k + fb + s2 * 4]);
            u32x2 pk;
            pk[0] = (u32)f2bf(w[0]) | ((u32)f2bf(w[1]) << 16);
            pk[1] = (u32)f2bf(w[2]) | ((u32)f2bf(w[3]) << 16);
            *(u32x2*)(&Bs[sr * 72 + fb + s2 * 4]) = pk;
        }
        __syncthreads();
#pragma unroll
        for (int ks = 0; ks < 2; ++ks) {
            bf16x8 af[2], bfr[2];
#pragma unroll
            for (int t = 0; t < 2; ++t) {
                af[t]  = *(const bf16x8*)(&As[(wm * 32 + t * 16 + row16) * 72 + ks * 32 + quad * 8]);
                bfr[t] = *(const bf16x8*)(&Bs[(wn * 32 + t * 16 + row16) * 72 + ks * 32 + quad * 8]);
            }
#pragma unroll
            for (int tm = 0; tm < 2; tm++)
#pragma unroll
                for (int tn = 0; tn < 2; tn++)
                    acc[tm][tn] = __builtin_amdgcn_mfma_f32_16x16x32_bf16(
                        af[tm], bfr[tn], acc[tm][tn], 0, 0, 0);
        }
        __syncthreads();
    }

#pragma unroll
    for (int tm = 0; tm < 2; tm++) {
#pragma unroll
        for (int tn = 0; tn < 2; tn++) {
            const int col = j0 + wn * 32 + tn * 16 + row16;
#pragma unroll
            for (int r = 0; r < 4; r++) {
                const int row = e0 + wm * 32 + tm * 16 + quad * 4 + r;
                M2[(size_t)row * F_DIM + col] = f2bf(acc[tm][tn][r]);
            }
        }
    }
}

// ---------------------------------------------------------------------------
// spmm2 — out[n][j] = rsqrt(dv[n]) * sum_{e in n} M2[e][j] + b[j].
// Wave per node; nlist staged to LDS; half-wave-paired 16 B gathers of the
// 512 KB L2/L3-resident M2. Plane-split reduce, same-wave combine.
// ---------------------------------------------------------------------------
__global__ __launch_bounds__(256) void spmm2(
    const u16* __restrict__ M2, const float* __restrict__ dv,
    const u16* __restrict__ nlist, const float* __restrict__ bias,
    float* __restrict__ out) {
    __shared__ u16 nl[4 * NMAX];
    __shared__ float red2[4][2][2][128];
    const int tid = threadIdx.x;
    const int wv = tid >> 6, lane = tid & 63;
    const int n = blockIdx.x * 4 + wv;
    if (tid < 256)
        ((u32*)nl)[tid] = ((const u32*)&nlist[(size_t)blockIdx.x * 4 * NMAX])[tid];
    __syncthreads();
    const float dvn = dv[n];
    const int cnt = min((int)dvn, NMAX);
    const u16* lst = &nl[wv * NMAX];
    const int half = lane >> 5;
    const int l32 = lane & 31;
    float a[8] = {};
    const int npairs = (cnt + 1) >> 1;
#pragma unroll 4
    for (int p = 0; p < npairs; ++p) {
        const int idx = 2 * p + half;
        if (idx < cnt) {
            const int e = lst[idx];
            const u32x4 pk = *(const u32x4*)(&M2[(size_t)e * F_DIM + l32 * 8]);
            a[0] += bflo(pk[0]); a[1] += bfhi(pk[0]);
            a[2] += bflo(pk[1]); a[3] += bfhi(pk[1]);
            a[4] += bflo(pk[2]); a[5] += bfhi(pk[2]);
            a[6] += bflo(pk[3]); a[7] += bfhi(pk[3]);
        }
    }
    f32x4 r0 = {a[0], a[1], a[2], a[3]};
    f32x4 r1 = {a[4], a[5], a[6], a[7]};
    *(f32x4*)(&red2[wv][half][0][l32 * 4]) = r0;
    *(f32x4*)(&red2[wv][half][1][l32 * 4]) = r1;
    // same-wave producer/consumer: lgkmcnt ordering suffices, no barrier
    const float s = rsqrtf(dvn);
    const f32x4 bb = *(const f32x4*)(&bias[lane * 4]);
    // col f = lane*4+k: plane = lane&1, idx = (lane>>1)*4 + k
    const f32x4 v0 = *(const f32x4*)(&red2[wv][0][lane & 1][(lane >> 1) * 4]);
    const f32x4 v1 = *(const f32x4*)(&red2[wv][1][lane & 1][(lane >> 1) * 4]);
    f32x4 r;
#pragma unroll
    for (int k = 0; k < 4; ++k) r[k] = (v0[k] + v1[k]) * s + bb[k];
    *(f32x4*)(&out[(size_t)n * F_DIM + lane * 4]) = r;
}

// ---------------------------------------------------------------------------
extern "C" void kernel_launch(void* const* d_in, const int* in_sizes, int n_in,
                              void* d_out, int out_size, void* d_ws, size_t ws_size,
                              hipStream_t stream) {
    (void)in_sizes; (void)n_in; (void)out_size; (void)ws_size;
    const float* X = (const float*)d_in[0];   // [8192 x 256]
    const float* H = (const float*)d_in[1];   // [8192 x 1024]
    const float* W = (const float*)d_in[2];   // [256 x 256]
    const float* b = (const float*)d_in[3];   // [256]
    float* out = (float*)d_out;               // [8192 x 256] fp32

    char* ws = (char*)d_ws;
    float* dv    = (float*)(ws);               // 32 KB  [8192]
    u32*   HbT   = (u32*)(ws + 0x10000);       // 1 MB   [1024][256] u32 bitmask
    u16*   nlist = (u16*)(ws + 0x110000);      // 2 MB   [8192][128]
    u16*   Xs    = (u16*)(ws + 0x310000);      // 4 MB   [8192][256] bf16
    u16*   Mb    = (u16*)(ws + 0x710000);      // 512 KB [1024][256] bf16 (has /de)
    u16*   M2    = (u16*)(ws + 0x790000);      // 512 KB [1024][256] bf16

    prep<<<NSEG, 512, 0, stream>>>(H, X, dv, nlist, Xs, HbT);
    spmm1<<<N_EDGES, 512, 0, stream>>>(Xs, HbT, Mb);
    gemm_we<<<dim3(4, 16), 256, 0, stream>>>(Mb, W, M2);
    spmm2<<<N_NODES / 4, 256, 0, stream>>>(M2, dv, nlist, b, out);
}